// Round 1
// baseline (5492.179 us; speedup 1.0000x reference)
//
#include <hip/hip_runtime.h>

#define D 128          // D_IN == D_OUT == 128
#define GEMM_ROWS 32   // rows per block in the dense GEMM

// -------- Stage 1: support = x @ W ----------------------------------------
// 256 threads/block. W (128x128 fp32, 64KB) staged in LDS once per block,
// x tile (32 rows, 16KB) staged in LDS. Each thread computes a 4-row x 4-col
// strip: c4 = (t&31) -> cols 4c..4c+3, rg = t>>5 -> rows rg*4..rg*4+3.
__global__ __launch_bounds__(256) void gcn_gemm(const float* __restrict__ x,
                                                const float* __restrict__ w,
                                                float* __restrict__ support,
                                                int n_nodes) {
    __shared__ float w_lds[D][D];          // 64 KB
    __shared__ float x_lds[GEMM_ROWS][D];  // 16 KB
    const int t = threadIdx.x;

    // Load W: 16384 floats = 4096 float4 / 256 threads = 16 each (coalesced)
    {
        const float4* w4 = (const float4*)w;
        float4* wl = (float4*)&w_lds[0][0];
#pragma unroll
        for (int i = 0; i < 16; ++i) wl[t + 256 * i] = w4[t + 256 * i];
    }
    // Load x tile: 32*128 floats = 1024 float4 / 256 threads = 4 each
    const long row_base = (long)blockIdx.x * GEMM_ROWS;
    {
        const float4* x4 = (const float4*)(x + row_base * D);
        float4* xl = (float4*)&x_lds[0][0];
#pragma unroll
        for (int i = 0; i < 4; ++i) xl[t + 256 * i] = x4[t + 256 * i];
    }
    __syncthreads();

    const int c = t & 31;   // float4 column group: cols 4c..4c+3
    const int rg = t >> 5;  // row group: rows rg*4 .. rg*4+3

    float4 acc[4];
#pragma unroll
    for (int j = 0; j < 4; ++j) acc[j] = make_float4(0.f, 0.f, 0.f, 0.f);

#pragma unroll 4
    for (int k = 0; k < D; ++k) {
        const float4 wv = ((const float4*)&w_lds[k][0])[c];
#pragma unroll
        for (int j = 0; j < 4; ++j) {
            const float xv = x_lds[rg * 4 + j][k];   // LDS broadcast
            acc[j].x += xv * wv.x;
            acc[j].y += xv * wv.y;
            acc[j].z += xv * wv.z;
            acc[j].w += xv * wv.w;
        }
    }

    float4* out4 = (float4*)(support + row_base * D);
#pragma unroll
    for (int j = 0; j < 4; ++j) out4[(rg * 4 + j) * 32 + c] = acc[j];
}

// -------- Stage 2: out[n][d] = bias[d] ------------------------------------
__global__ __launch_bounds__(256) void gcn_init_out(const float* __restrict__ bias,
                                                    float* __restrict__ out,
                                                    long n4) {
    const long i = (long)blockIdx.x * blockDim.x + threadIdx.x;
    if (i >= n4) return;
    ((float4*)out)[i] = ((const float4*)bias)[i & 31];  // 128 floats = 32 float4
}

// -------- Stage 3: out[row[e]] += val[e] * support[col[e]] ----------------
// 32 threads per edge, float4 per thread (128 cols = 32 lanes * 4).
__global__ __launch_bounds__(256) void gcn_scatter(const float* __restrict__ support,
                                                   const int* __restrict__ erow,
                                                   const int* __restrict__ ecol,
                                                   const float* __restrict__ eval,
                                                   float* __restrict__ out,
                                                   int n_edges) {
    const int t = threadIdx.x;
    const int e = blockIdx.x * 8 + (t >> 5);
    if (e >= n_edges) return;
    const int lane = t & 31;

    const int r = erow[e];
    const int c = ecol[e];
    const float v = eval[e];

    const float4 s = ((const float4*)support)[(long)c * 32 + lane];
    float* o = out + (long)r * D + lane * 4;
    unsafeAtomicAdd(o + 0, v * s.x);
    unsafeAtomicAdd(o + 1, v * s.y);
    unsafeAtomicAdd(o + 2, v * s.z);
    unsafeAtomicAdd(o + 3, v * s.w);
}

extern "C" void kernel_launch(void* const* d_in, const int* in_sizes, int n_in,
                              void* d_out, int out_size, void* d_ws, size_t ws_size,
                              hipStream_t stream) {
    const float* x    = (const float*)d_in[0];
    const float* w    = (const float*)d_in[1];
    const float* bias = (const float*)d_in[2];
    const int* erow   = (const int*)d_in[3];
    const int* ecol   = (const int*)d_in[4];
    const float* eval = (const float*)d_in[5];

    const int n_nodes = in_sizes[0] / D;   // 100000
    const int n_edges = in_sizes[3];       // 3200000

    float* support = (float*)d_ws;         // n_nodes * 128 fp32 = 51.2 MB
    float* out = (float*)d_out;

    // Stage 1: support = x @ W
    gcn_gemm<<<(n_nodes + GEMM_ROWS - 1) / GEMM_ROWS, 256, 0, stream>>>(
        x, w, support, n_nodes);

    // Stage 2: out = bias (broadcast)
    const long n4 = (long)n_nodes * D / 4;
    gcn_init_out<<<(int)((n4 + 255) / 256), 256, 0, stream>>>(bias, out, n4);

    // Stage 3: scatter-add messages
    gcn_scatter<<<(n_edges + 7) / 8, 256, 0, stream>>>(
        support, erow, ecol, eval, out, n_edges);
}

// Round 2
// 920.950 us; speedup vs baseline: 5.9636x; 5.9636x over previous
//
#include <hip/hip_runtime.h>

#define D 128          // D_IN == D_OUT == 128
#define GEMM_ROWS 32   // rows per block in the dense GEMM

// -------- Stage 1: support = x @ W ----------------------------------------
__global__ __launch_bounds__(256) void gcn_gemm(const float* __restrict__ x,
                                                const float* __restrict__ w,
                                                float* __restrict__ support,
                                                int n_nodes) {
    __shared__ float w_lds[D][D];          // 64 KB
    __shared__ float x_lds[GEMM_ROWS][D];  // 16 KB
    const int t = threadIdx.x;

    {
        const float4* w4 = (const float4*)w;
        float4* wl = (float4*)&w_lds[0][0];
#pragma unroll
        for (int i = 0; i < 16; ++i) wl[t + 256 * i] = w4[t + 256 * i];
    }
    const long row_base = (long)blockIdx.x * GEMM_ROWS;
    {
        const float4* x4 = (const float4*)(x + row_base * D);
        float4* xl = (float4*)&x_lds[0][0];
#pragma unroll
        for (int i = 0; i < 4; ++i) xl[t + 256 * i] = x4[t + 256 * i];
    }
    __syncthreads();

    const int c = t & 31;
    const int rg = t >> 5;

    float4 acc[4];
#pragma unroll
    for (int j = 0; j < 4; ++j) acc[j] = make_float4(0.f, 0.f, 0.f, 0.f);

#pragma unroll 4
    for (int k = 0; k < D; ++k) {
        const float4 wv = ((const float4*)&w_lds[k][0])[c];
#pragma unroll
        for (int j = 0; j < 4; ++j) {
            const float xv = x_lds[rg * 4 + j][k];
            acc[j].x += xv * wv.x;
            acc[j].y += xv * wv.y;
            acc[j].z += xv * wv.z;
            acc[j].w += xv * wv.w;
        }
    }

    float4* out4 = (float4*)(support + row_base * D);
#pragma unroll
    for (int j = 0; j < 4; ++j) out4[(rg * 4 + j) * 32 + c] = acc[j];
}

// -------- Stage 2: histogram of edge rows into rp[0..n) --------------------
__global__ __launch_bounds__(256) void gcn_hist(const int* __restrict__ erow,
                                                int* __restrict__ rp,
                                                int n_edges) {
    const int e = blockIdx.x * blockDim.x + threadIdx.x;
    if (e < n_edges) atomicAdd(&rp[erow[e]], 1);
}

// -------- Stage 3: in-place exclusive scan (single block) ------------------
// rp[0..n) counts -> rp[i] = exclusive prefix; rp[n] = total.
__global__ __launch_bounds__(1024) void gcn_scan(int* __restrict__ rp, int n) {
    __shared__ int sdata[1024];
    const int t = threadIdx.x;
    const int chunk = (n + 1023) >> 10;
    const int beg = t * chunk;
    const int end = min(beg + chunk, n);

    int sum = 0;
    for (int i = beg; i < end; ++i) sum += rp[i];
    sdata[t] = sum;
    __syncthreads();
    for (int off = 1; off < 1024; off <<= 1) {
        const int v = (t >= off) ? sdata[t - off] : 0;
        __syncthreads();
        sdata[t] += v;
        __syncthreads();
    }
    int running = sdata[t] - sum;  // exclusive base for this thread's chunk
    if (t == 1023) rp[n] = sdata[1023];
    for (int i = beg; i < end; ++i) {
        const int c = rp[i];
        rp[i] = running;
        running += c;
    }
}

// -------- Stage 4: bucket edges by row (CSR fill) --------------------------
// After this kernel, rp[r] == end-offset of row r (== original rp[r+1]).
__global__ __launch_bounds__(256) void gcn_fill(const int* __restrict__ erow,
                                                const int* __restrict__ ecol,
                                                const float* __restrict__ eval,
                                                int* __restrict__ rp,
                                                int2* __restrict__ packed,
                                                int n_edges) {
    const int e = blockIdx.x * blockDim.x + threadIdx.x;
    if (e >= n_edges) return;
    const int r = erow[e];
    const int pos = atomicAdd(&rp[r], 1);
    packed[pos] = make_int2(ecol[e], __float_as_int(eval[e]));
}

// -------- Stage 5: out[r] = bias + sum_{e in row r} v_e * support[c_e] -----
// 32 lanes per row (128 cols = 32 x float4); 8 rows per 256-thread block.
__global__ __launch_bounds__(256) void gcn_aggregate(const float* __restrict__ support,
                                                     const int2* __restrict__ packed,
                                                     const int* __restrict__ rp,
                                                     const float* __restrict__ bias,
                                                     float* __restrict__ out,
                                                     int n_nodes) {
    const int t = threadIdx.x;
    const int lane = t & 31;
    const int r = blockIdx.x * 8 + (t >> 5);
    if (r >= n_nodes) return;

    const int start = (r == 0) ? 0 : rp[r - 1];
    const int end = rp[r];

    float4 acc = ((const float4*)bias)[lane];
    const float4* s4 = (const float4*)support;

    for (int base = start; base < end; base += 32) {
        const int nn = min(32, end - base);
        int2 ed = make_int2(0, 0);
        if (lane < nn) ed = packed[base + lane];   // coalesced 8B/lane
#pragma unroll 4
        for (int j = 0; j < nn; ++j) {
            const int c = __shfl(ed.x, j, 32);
            const float v = __int_as_float(__shfl(ed.y, j, 32));
            const float4 s = s4[(long)c * 32 + lane];
            acc.x += v * s.x;
            acc.y += v * s.y;
            acc.z += v * s.z;
            acc.w += v * s.w;
        }
    }
    ((float4*)out)[(long)r * 32 + lane] = acc;
}

extern "C" void kernel_launch(void* const* d_in, const int* in_sizes, int n_in,
                              void* d_out, int out_size, void* d_ws, size_t ws_size,
                              hipStream_t stream) {
    const float* x    = (const float*)d_in[0];
    const float* w    = (const float*)d_in[1];
    const float* bias = (const float*)d_in[2];
    const int* erow   = (const int*)d_in[3];
    const int* ecol   = (const int*)d_in[4];
    const float* eval = (const float*)d_in[5];

    const int n_nodes = in_sizes[0] / D;   // 100000
    const int n_edges = in_sizes[3];       // 3200000

    // Workspace layout: support | rp | packed edges  (~77.2 MB total)
    char* ws = (char*)d_ws;
    float* support = (float*)ws;
    size_t off = (size_t)n_nodes * D * sizeof(float);
    int* rp = (int*)(ws + off);
    off += ((size_t)(n_nodes + 1) * sizeof(int) + 15) & ~(size_t)15;
    int2* packed = (int2*)(ws + off);

    float* out = (float*)d_out;

    // 1. support = x @ W
    gcn_gemm<<<(n_nodes + GEMM_ROWS - 1) / GEMM_ROWS, 256, 0, stream>>>(
        x, w, support, n_nodes);

    // 2-4. Build CSR: zero counts, histogram, scan, fill
    hipMemsetAsync(rp, 0, (size_t)(n_nodes + 1) * sizeof(int), stream);
    gcn_hist<<<(n_edges + 255) / 256, 256, 0, stream>>>(erow, rp, n_edges);
    gcn_scan<<<1, 1024, 0, stream>>>(rp, n_nodes);
    gcn_fill<<<(n_edges + 255) / 256, 256, 0, stream>>>(
        erow, ecol, eval, rp, packed, n_edges);

    // 5. Gather-aggregate: one 32-lane group per row, registers only
    gcn_aggregate<<<(n_nodes + 7) / 8, 256, 0, stream>>>(
        support, packed, rp, bias, out, n_nodes);
}